// Round 5
// baseline (366.900 us; speedup 1.0000x reference)
//
#include <hip/hip_runtime.h>
#include <math.h>
#include <float.h>

#define L_   4096
#define M_   8192
#define H_   8
#define D_   64
#define KK   45          // 5 * ceil(ln(4096))

// ws layout in float2 units
#define WS_C   0         // c[4096]  : e^{-i pi j^2 / 8191}
#define WS_D   4096      // d[4096]  : e^{+i pi j^2 / 8190}
#define WS_TW  8192      // tw[8192] : e^{-2 pi i j / 8192}
#define WS_H1  16384     // H1s[8192]: DIF-FFT(conj-chirp c), pre-scaled 1/8192, digit-reversed
#define WS_H2  24576     // H2s[8192]: same for d

__device__ __forceinline__ float2 cadd(float2 a, float2 b) { return make_float2(a.x + b.x, a.y + b.y); }
__device__ __forceinline__ float2 csub(float2 a, float2 b) { return make_float2(a.x - b.x, a.y - b.y); }
__device__ __forceinline__ float2 cmulf(float2 a, float2 b) {
  return make_float2(a.x * b.x - a.y * b.y, a.x * b.y + a.y * b.x);
}
__device__ __forceinline__ float2 cmulcf(float2 a, float2 b) {  // a * conj(b)
  return make_float2(a.x * b.x + a.y * b.y, a.y * b.x - a.x * b.y);
}

// ---------------- radix-4 DIF with per-stage hook: natural in -> digit-reversed out ----
// hook() is called once per stage (7 calls total), right after the stage barrier.
template <int NT, typename F>
static __device__ void fft_dif_h(float2* buf, const float2* __restrict__ tw, F&& hook) {
  const int tid = threadIdx.x;
  #pragma unroll
  for (int s = 0; s < 6; ++s) {
    const int q = 2048 >> (2 * s);
    __syncthreads();
    hook();
    #pragma unroll
    for (int r = 0; r < 2048 / NT; ++r) {
      const int bid = tid + r * NT;
      const int j   = bid & (q - 1);
      const int i0  = ((bid >> (11 - 2 * s)) << (13 - 2 * s)) + j;
      const int e   = j << (2 * s);
      const float2 w1 = tw[e], w2 = tw[2 * e], w3 = tw[3 * e];
      const float2 a = buf[i0], b = buf[i0 + q], c = buf[i0 + 2 * q], d = buf[i0 + 3 * q];
      const float2 t0 = cadd(a, c), t1 = csub(a, c), t2 = cadd(b, d), t3 = csub(b, d);
      buf[i0]         = cadd(t0, t2);
      buf[i0 + q]     = cmulf(make_float2(t1.x + t3.y, t1.y - t3.x), w1);  // (t1 - i t3) w1
      buf[i0 + 2 * q] = cmulf(csub(t0, t2), w2);
      buf[i0 + 3 * q] = cmulf(make_float2(t1.x - t3.y, t1.y + t3.x), w3);  // (t1 + i t3) w3
    }
  }
  __syncthreads();
  hook();
  #pragma unroll
  for (int r = 0; r < 4096 / NT; ++r) {
    const int i0 = (tid + r * NT) << 1;
    const float2 a = buf[i0], b = buf[i0 + 1];
    buf[i0] = cadd(a, b); buf[i0 + 1] = csub(a, b);
  }
  __syncthreads();
}

// ---------------- radix-4 DIT inverse with hook: exact stage-mirror of fft_dif_h ------
// fft_dit_inv_h(fft_dif_h(x)) = 8192 * x (scale folded into H1s/H2s). 7 hook calls.
template <int NT, typename F>
static __device__ void fft_dit_inv_h(float2* buf, const float2* __restrict__ tw, F&& hook) {
  const int tid = threadIdx.x;
  __syncthreads();
  hook();
  #pragma unroll
  for (int r = 0; r < 4096 / NT; ++r) {
    const int i0 = (tid + r * NT) << 1;
    const float2 a = buf[i0], b = buf[i0 + 1];
    buf[i0] = cadd(a, b); buf[i0 + 1] = csub(a, b);
  }
  #pragma unroll
  for (int s = 5; s >= 0; --s) {
    const int q = 2048 >> (2 * s);
    __syncthreads();
    hook();
    #pragma unroll
    for (int r = 0; r < 2048 / NT; ++r) {
      const int bid = tid + r * NT;
      const int j   = bid & (q - 1);
      const int i0  = ((bid >> (11 - 2 * s)) << (13 - 2 * s)) + j;
      const int e   = j << (2 * s);
      const float2 w1 = tw[e], w2 = tw[2 * e], w3 = tw[3 * e];
      const float2 z0 = buf[i0];
      const float2 z1 = cmulcf(buf[i0 + q],     w1);
      const float2 z2 = cmulcf(buf[i0 + 2 * q], w2);
      const float2 z3 = cmulcf(buf[i0 + 3 * q], w3);
      const float2 t0 = cadd(z0, z2), t1 = csub(z0, z2), t2 = cadd(z1, z3), u = csub(z1, z3);
      buf[i0]         = cadd(t0, t2);
      buf[i0 + q]     = make_float2(t1.x - u.y, t1.y + u.x);   // t1 + i u
      buf[i0 + 2 * q] = csub(t0, t2);
      buf[i0 + 3 * q] = make_float2(t1.x + u.y, t1.y - u.x);   // t1 - i u
    }
  }
  __syncthreads();
}

extern "C" __global__ void setup_tables(float2* ws) {
  const int idx = blockIdx.x * 512 + threadIdx.x;
  if (idx < 4096) {
    const long p = ((long)idx * idx) % 16382;      // j^2 mod 2*8191
    const double th = -M_PI * (double)p / 8191.0;
    double s, c; sincos(th, &s, &c);
    ws[WS_C + idx] = make_float2((float)c, (float)s);
  } else if (idx < 8192) {
    const int j = idx - 4096;
    const long p = ((long)j * j) % 16380;          // j^2 mod 2*8190
    const double th = M_PI * (double)p / 8190.0;
    double s, c; sincos(th, &s, &c);
    ws[WS_D + j] = make_float2((float)c, (float)s);
  } else if (idx < 16384) {
    const int j = idx - 8192;
    const double th = -M_PI * (double)j / 4096.0;  // e^{-2pi i j/8192}
    double s, c; sincos(th, &s, &c);
    ws[WS_TW + j] = make_float2((float)c, (float)s);
  }
}

extern "C" __global__ __launch_bounds__(512, 1) void setup_filters(float2* ws) {
  __shared__ float2 buf[M_];
  const float2* src = ws + (blockIdx.x == 0 ? WS_C : WS_D);
  float2*       dst = ws + (blockIdx.x == 0 ? WS_H1 : WS_H2);
  const float2* tw  = ws + WS_TW;
  for (int i = threadIdx.x; i < M_; i += 512) {
    float2 val = make_float2(0.f, 0.f);
    if (i != 4096) {                       // kernel support |j| <= 4095
      const int jj = (i <= 4095) ? i : (M_ - i);   // chirp is even in j
      const float2 e = src[jj];
      val = make_float2(e.x, -e.y);        // conj(chirp)
    }
    buf[i] = val;
  }
  fft_dif_h<512>(buf, tw, [] __device__ () {});
  const float sc = 1.0f / 8192.0f;         // fold IFFT scaling into the filter
  for (int i = threadIdx.x; i < M_; i += 512)
    dst[i] = make_float2(buf[i].x * sc, buf[i].y * sc);
}

// ---------------- fused kernel: projections pipelined into the CZT stages ----------------
extern "C" __global__ __launch_bounds__(1024, 4)
void autocorr_fused(const float* __restrict__ queries, const float* __restrict__ keys,
                    const float* __restrict__ values,
                    const float* __restrict__ Wq, const float* __restrict__ bq,
                    const float* __restrict__ Wk, const float* __restrict__ bk,
                    const float* __restrict__ Wv, const float* __restrict__ bv,
                    const float2* __restrict__ ws, float* __restrict__ outp)
{
  __shared__ float2 bufA[M_];       // 64 KB (K path, then inverse-CZT); k parks in pad region
  __shared__ float2 bufB[M_];       // 64 KB (Q path); q parks in pad region (floats 8192..12287)
  __shared__ float  v_lds[L_];      // 16 KB (v streams in during Q-CZT)
  __shared__ float  cand_v[16 * KK];
  __shared__ int    cand_i[16 * KK];
  __shared__ float  w_sh[KK];
  __shared__ int    i_sh[KK];

  const int tid = threadIdx.x;
  const int bh  = blockIdx.x;
  const int b   = bh >> 3;
  const int h   = bh & 7;
  const int lane16 = tid & 15;
  const int grp    = tid >> 4;      // 0..63 (1024 threads): chunk c covers l = (c<<6)+grp

  const float2* c_t = ws + WS_C;
  const float2* d_t = ws + WS_D;
  const float2* tw  = ws + WS_TW;
  const float2* H1  = ws + WS_H1;
  const float2* H2  = ws + WS_H2;

  const size_t rowoff = ((size_t)b * L_ * H_ + h) * (size_t)D_;
  const float* Xq = queries + rowoff;
  const float* Xk = keys    + rowoff;
  const float* Xv = values  + rowoff;
  const float4 w4q = reinterpret_cast<const float4*>(Wq)[lane16];
  const float4 w4k = reinterpret_cast<const float4*>(Wk)[lane16];
  const float4 w4v = reinterpret_cast<const float4*>(Wv)[lane16];
  const float bq0 = bq[0], bk0 = bk[0], bv0 = bv[0];

  float* kst = reinterpret_cast<float*>(bufA) + 8192;   // k row parking (zero-pad region)
  float* qst = reinterpret_cast<float*>(bufB) + 8192;   // q row parking

  // ---------------- phase 0: stream-project k (64 chunks, 2x8 double-banked) ----------------
  {
    float4 KA[8], KB[8];
    #pragma unroll
    for (int u = 0; u < 8; ++u)
      KA[u] = reinterpret_cast<const float4*>(Xk + (size_t)((u << 6) + grp) * 512)[lane16];
    #pragma unroll
    for (int q4 = 0; q4 < 4; ++q4) {
      const int base = q4 * 16;
      #pragma unroll
      for (int u = 0; u < 8; ++u)
        KB[u] = reinterpret_cast<const float4*>(Xk + (size_t)(((base + 8 + u) << 6) + grp) * 512)[lane16];
      #pragma unroll
      for (int u = 0; u < 8; ++u) {
        float vv = KA[u].x * w4k.x + KA[u].y * w4k.y + KA[u].z * w4k.z + KA[u].w * w4k.w;
        vv += __shfl_xor(vv, 1); vv += __shfl_xor(vv, 2);
        vv += __shfl_xor(vv, 4); vv += __shfl_xor(vv, 8);
        if (lane16 == 0) kst[((base + u) << 6) + grp] = vv + bk0;
      }
      if (q4 < 3) {
        #pragma unroll
        for (int u = 0; u < 8; ++u)
          KA[u] = reinterpret_cast<const float4*>(Xk + (size_t)(((base + 16 + u) << 6) + grp) * 512)[lane16];
      }
      #pragma unroll
      for (int u = 0; u < 8; ++u) {
        float vv = KB[u].x * w4k.x + KB[u].y * w4k.y + KB[u].z * w4k.z + KB[u].w * w4k.w;
        vv += __shfl_xor(vv, 1); vv += __shfl_xor(vv, 2);
        vv += __shfl_xor(vv, 4); vv += __shfl_xor(vv, 8);
        if (lane16 == 0) kst[((base + 8 + u) << 6) + grp] = vv + bk0;
      }
    }
  }
  __syncthreads();
  float kv[4];
  #pragma unroll
  for (int r = 0; r < 4; ++r) kv[r] = kst[tid + (r << 10)];
  __syncthreads();                       // all reads done before pad region overwritten
  #pragma unroll
  for (int r = 0; r < 4; ++r) {
    const int i = tid + (r << 10);
    const float2 cc = c_t[i];
    bufA[i] = make_float2(kv[r] * cc.x, kv[r] * cc.y);
  }
  #pragma unroll
  for (int r = 4; r < 8; ++r) bufA[tid + (r << 10)] = make_float2(0.f, 0.f);

  // ---------------- q prefetch hook (rides under K-CZT; 15 stage slots + 1 manual) ----------
  int cq = 0;
  float4 pfq[4];
  auto issueQ = [&](int cb) {
    #pragma unroll
    for (int u = 0; u < 4; ++u)
      pfq[u] = reinterpret_cast<const float4*>(Xq + (size_t)(((cb + u) << 6) + grp) * 512)[lane16];
  };
  auto hookQ = [&]() {
    #pragma unroll
    for (int u = 0; u < 4; ++u) {
      float vv = pfq[u].x * w4q.x + pfq[u].y * w4q.y + pfq[u].z * w4q.z + pfq[u].w * w4q.w;
      vv += __shfl_xor(vv, 1); vv += __shfl_xor(vv, 2);
      vv += __shfl_xor(vv, 4); vv += __shfl_xor(vv, 8);
      if (lane16 == 0) qst[((cq + u) << 6) + grp] = vv + bq0;
    }
    cq += 4;
    if (cq < 64) issueQ(cq);
  };
  issueQ(0);

  // ---------------- K forward CZT: K~ = IFFT(FFT(k*c) . H1) ----------------
  fft_dif_h<1024>(bufA, tw, hookQ);           // 7 hook calls
  hookQ();                                    // 8th
  #pragma unroll
  for (int r = 0; r < 8; ++r) { const int i = tid + (r << 10); bufA[i] = cmulf(bufA[i], H1[i]); }
  fft_dit_inv_h<1024>(bufA, tw, hookQ);       // 7 more (15 total)
  hookQ();                                    // 16th: chunks 60..63 (no further issue)

  float2 Kr[4];
  #pragma unroll
  for (int r = 0; r < 4; ++r) { const int m = tid + (r << 10); Kr[r] = cmulf(c_t[m], bufA[m]); }

  // ---------------- q -> bufB (chirped), v prefetch hook armed ----------------
  __syncthreads();                       // last hookQ writes visible
  float qv[4];
  #pragma unroll
  for (int r = 0; r < 4; ++r) qv[r] = qst[tid + (r << 10)];
  __syncthreads();
  #pragma unroll
  for (int r = 0; r < 4; ++r) {
    const int i = tid + (r << 10);
    const float2 cc = c_t[i];
    bufB[i] = make_float2(qv[r] * cc.x, qv[r] * cc.y);
  }
  #pragma unroll
  for (int r = 4; r < 8; ++r) bufB[tid + (r << 10)] = make_float2(0.f, 0.f);

  int cv = 0;
  float4 pfv[4];
  auto issueV = [&](int cb) {
    #pragma unroll
    for (int u = 0; u < 4; ++u)
      pfv[u] = reinterpret_cast<const float4*>(Xv + (size_t)(((cb + u) << 6) + grp) * 512)[lane16];
  };
  auto hookV = [&]() {
    #pragma unroll
    for (int u = 0; u < 4; ++u) {
      float vv = pfv[u].x * w4v.x + pfv[u].y * w4v.y + pfv[u].z * w4v.z + pfv[u].w * w4v.w;
      vv += __shfl_xor(vv, 1); vv += __shfl_xor(vv, 2);
      vv += __shfl_xor(vv, 4); vv += __shfl_xor(vv, 8);
      if (lane16 == 0) v_lds[((cv + u) << 6) + grp] = vv + bv0;
    }
    cv += 4;
    if (cv < 64) issueV(cv);
  };
  issueV(0);

  // ---------------- Q forward CZT (v streams in underneath) ----------------
  fft_dif_h<1024>(bufB, tw, hookV);
  hookV();
  #pragma unroll
  for (int r = 0; r < 8; ++r) { const int i = tid + (r << 10); bufB[i] = cmulf(bufB[i], H1[i]); }
  fft_dit_inv_h<1024>(bufB, tw, hookV);
  hookV();                                    // 16th: chunks 60..63

  // ---------------- F = (c.Q~) * conj(K); build g.d into bufA ----------------
  #pragma unroll
  for (int r = 0; r < 4; ++r) {
    const int m = tid + (r << 10);
    const float2 cc = c_t[m];
    const float2 Q = cmulf(cc, bufB[m]);
    const float2 F = cmulcf(Q, Kr[r]);
    float2 g;
    if (m == 0 || m == 4095) g = make_float2(F.x, 0.f);   // DC/Nyquist: Im dropped
    else                     g = make_float2(2.f * F.x, 2.f * F.y);
    bufA[m] = cmulf(g, d_t[m]);
  }
  #pragma unroll
  for (int r = 4; r < 8; ++r) bufA[tid + (r << 10)] = make_float2(0.f, 0.f);

  // ---------------- inverse via irfft_8190 semantics ----------------
  auto noh = [] __device__ () {};
  fft_dif_h<1024>(bufA, tw, noh);
  #pragma unroll
  for (int r = 0; r < 8; ++r) { const int i = tid + (r << 10); bufA[i] = cmulf(bufA[i], H2[i]); }
  fft_dit_inv_h<1024>(bufA, tw, noh);

  // ---------------- scores + per-wave top-45 ----------------
  const float SCALE = (float)(1.0 / (8190.0 * 4096.0));   // /8190 (irfft) then /4096 (L)
  float svv[4]; int sii[4];
  #pragma unroll
  for (int r = 0; r < 4; ++r) {
    const int t = tid + (r << 10);
    const float2 Z = cmulf(d_t[t], bufA[t]);
    svv[r] = Z.x * SCALE;
    sii[r] = t;
  }
  const int lane = tid & 63, wv = tid >> 6;   // 16 waves
  for (int it = 0; it < KK; ++it) {
    float bvv = -FLT_MAX; int bii = 0x7fffffff;
    #pragma unroll
    for (int c = 0; c < 4; ++c)
      if (svv[c] > bvv || (svv[c] == bvv && sii[c] < bii)) { bvv = svv[c]; bii = sii[c]; }
    #pragma unroll
    for (int off = 1; off < 64; off <<= 1) {
      const float ov = __shfl_xor(bvv, off);
      const int   oi = __shfl_xor(bii, off);
      if (ov > bvv || (ov == bvv && oi < bii)) { bvv = ov; bii = oi; }
    }
    #pragma unroll
    for (int c = 0; c < 4; ++c) if (sii[c] == bii) svv[c] = -FLT_MAX;
    if (lane == 0) { cand_v[wv * KK + it] = bvv; cand_i[wv * KK + it] = bii; }
  }
  __syncthreads();

  // ---------------- merge 16x45 + softmax (wave 0) ----------------
  if (tid < 64) {
    float mv[12]; int mi[12];
    #pragma unroll
    for (int c = 0; c < 12; ++c) {
      const int id = tid + 64 * c;
      if (id < 16 * KK) { mv[c] = cand_v[id]; mi[c] = cand_i[id]; }
      else              { mv[c] = -FLT_MAX;   mi[c] = 0x7fffffff; }
    }
    float m0 = 0.f, sum = 0.f, myv = -FLT_MAX; int myi = 0;
    for (int it = 0; it < KK; ++it) {
      float bvv = -FLT_MAX; int bii = 0x7fffffff;
      #pragma unroll
      for (int c = 0; c < 12; ++c)
        if (mv[c] > bvv || (mv[c] == bvv && mi[c] < bii)) { bvv = mv[c]; bii = mi[c]; }
      #pragma unroll
      for (int off = 1; off < 64; off <<= 1) {
        const float ov = __shfl_xor(bvv, off);
        const int   oi = __shfl_xor(bii, off);
        if (ov > bvv || (ov == bvv && oi < bii)) { bvv = ov; bii = oi; }
      }
      if (it == 0) m0 = bvv;
      sum += expf(bvv - m0);               // identical on all lanes
      if (tid == it) { myv = bvv; myi = bii; }
      #pragma unroll
      for (int c = 0; c < 12; ++c) if (mi[c] == bii) mv[c] = -FLT_MAX;
    }
    if (tid < KK) { w_sh[tid] = expf(myv - m0) / sum; i_sh[tid] = myi; }
  }
  __syncthreads();

  // ---------------- gather: out[t] = sum_j w_j * v[(idx_j + t) & 4095] ------------
  {
    float acc[4] = {0, 0, 0, 0};
    for (int j = 0; j < KK; ++j) {
      const float wj = w_sh[j];
      const int   bse = i_sh[j] + tid;
      #pragma unroll
      for (int r = 0; r < 4; ++r)
        acc[r] = fmaf(wj, v_lds[(bse + (r << 10)) & (L_ - 1)], acc[r]);
    }
    float* op = outp + ((size_t)bh << 12);
    #pragma unroll
    for (int r = 0; r < 4; ++r) op[tid + (r << 10)] = acc[r];
  }
}

extern "C" void kernel_launch(void* const* d_in, const int* in_sizes, int n_in,
                              void* d_out, int out_size, void* d_ws, size_t ws_size,
                              hipStream_t stream) {
  const float* queries = (const float*)d_in[0];
  const float* keys    = (const float*)d_in[1];
  const float* values  = (const float*)d_in[2];
  const float* Wq = (const float*)d_in[3];
  const float* bq = (const float*)d_in[4];
  const float* Wk = (const float*)d_in[5];
  const float* bk = (const float*)d_in[6];
  const float* Wv = (const float*)d_in[7];
  const float* bv = (const float*)d_in[8];
  float2* ws = (float2*)d_ws;
  float* out = (float*)d_out;

  hipLaunchKernelGGL(setup_tables,  dim3(32), dim3(512), 0, stream, ws);
  hipLaunchKernelGGL(setup_filters, dim3(2),  dim3(512), 0, stream, ws);
  hipLaunchKernelGGL(autocorr_fused, dim3(256), dim3(1024), 0, stream,
                     queries, keys, values, Wq, bq, Wk, bk, Wv, bv, ws, out);
}

// Round 7
// 340.039 us; speedup vs baseline: 1.0790x; 1.0790x over previous
//
#include <hip/hip_runtime.h>
#include <math.h>
#include <float.h>

#define L_   4096
#define M_   8192
#define H_   8
#define D_   64
#define KK   45          // 5 * ceil(ln(4096))

// ws layout in float2 units
#define WS_C   0         // c[4096]  : e^{-i pi j^2 / 8191}
#define WS_D   4096      // d[4096]  : e^{+i pi j^2 / 8190}
#define WS_TW  8192      // tw[8192] : e^{-2 pi i j / 8192} (fp64-accurate; setup_filters only)
#define WS_H1  16384     // H1s[8192]: DIF-FFT(conj-chirp c), pre-scaled 1/8192, digit-reversed
#define WS_H2  24576     // H2s[8192]: same for d
#define WS_QKV 32768     // float2 offset where staged q/k/v planes start
// tables: 256 KB; then q/k/v planes: 3 x 1M floats = 12 MB

__device__ __forceinline__ float2 cadd(float2 a, float2 b) { return make_float2(a.x + b.x, a.y + b.y); }
__device__ __forceinline__ float2 csub(float2 a, float2 b) { return make_float2(a.x - b.x, a.y - b.y); }
__device__ __forceinline__ float2 cmulf(float2 a, float2 b) {
  return make_float2(a.x * b.x - a.y * b.y, a.x * b.y + a.y * b.x);
}
__device__ __forceinline__ float2 cmulcf(float2 a, float2 b) {  // a * conj(b)
  return make_float2(a.x * b.x + a.y * b.y, a.y * b.x - a.x * b.y);
}

// register twiddle: e^{-2 pi i e / 8192}, e in [0, 2048)
__device__ __forceinline__ float2 twf(int e) {
  float s, c;
  __sincosf((float)e * -7.66990394e-4f, &s, &c);   // -2*pi/8192
  return make_float2(c, s);
}

#define R4DIF(BUF) { \
  const float2 a = BUF[i0], b = BUF[i0 + q], c = BUF[i0 + 2 * q], d = BUF[i0 + 3 * q]; \
  const float2 t0 = cadd(a, c), t1 = csub(a, c), t2 = cadd(b, d), t3 = csub(b, d); \
  BUF[i0]         = cadd(t0, t2); \
  BUF[i0 + q]     = cmulf(make_float2(t1.x + t3.y, t1.y - t3.x), w1); \
  BUF[i0 + 2 * q] = cmulf(csub(t0, t2), w2); \
  BUF[i0 + 3 * q] = cmulf(make_float2(t1.x - t3.y, t1.y + t3.x), w3); }

#define R4DIT(BUF) { \
  const float2 z0 = BUF[i0]; \
  const float2 z1 = cmulcf(BUF[i0 + q],     w1); \
  const float2 z2 = cmulcf(BUF[i0 + 2 * q], w2); \
  const float2 z3 = cmulcf(BUF[i0 + 3 * q], w3); \
  const float2 t0 = cadd(z0, z2), t1 = csub(z0, z2), t2 = cadd(z1, z3), u = csub(z1, z3); \
  BUF[i0]         = cadd(t0, t2); \
  BUF[i0 + q]     = make_float2(t1.x - u.y, t1.y + u.x); \
  BUF[i0 + 2 * q] = csub(t0, t2); \
  BUF[i0 + 3 * q] = make_float2(t1.x + u.y, t1.y - u.x); }

// fused r2 + H-pointwise + r2inv on one float2-pair packed in a float4
__device__ __forceinline__ float4 midpair(float4 a, float4 h) {
  float2 u = make_float2(a.x + a.z, a.y + a.w);
  float2 v = make_float2(a.x - a.z, a.y - a.w);
  u = cmulf(u, make_float2(h.x, h.y));
  v = cmulf(v, make_float2(h.z, h.w));
  return make_float4(u.x + v.x, u.y + v.y, u.x - v.x, u.y - v.y);
}

// full Bluestein convolution pass on TWO buffers (shared twiddles), 1024 threads
static __device__ void conv2(float2* A, float2* B, const float2* __restrict__ Hf) {
  const int tid = threadIdx.x;
  #pragma unroll
  for (int s = 0; s < 6; ++s) {
    const int q = 2048 >> (2 * s);
    __syncthreads();
    #pragma unroll
    for (int r = 0; r < 2; ++r) {
      const int bid = tid + (r << 10);
      const int j   = bid & (q - 1);
      const int i0  = ((bid >> (11 - 2 * s)) << (13 - 2 * s)) + j;
      const float2 w1 = twf(j << (2 * s));
      const float2 w2 = cmulf(w1, w1);
      const float2 w3 = cmulf(w2, w1);
      R4DIF(A) R4DIF(B)
    }
  }
  __syncthreads();
  #pragma unroll
  for (int r = 0; r < 4; ++r) {
    const int p = tid + (r << 10);
    const float4 h = reinterpret_cast<const float4*>(Hf)[p];
    reinterpret_cast<float4*>(A)[p] = midpair(reinterpret_cast<float4*>(A)[p], h);
    reinterpret_cast<float4*>(B)[p] = midpair(reinterpret_cast<float4*>(B)[p], h);
  }
  #pragma unroll
  for (int s = 5; s >= 0; --s) {
    const int q = 2048 >> (2 * s);
    __syncthreads();
    #pragma unroll
    for (int r = 0; r < 2; ++r) {
      const int bid = tid + (r << 10);
      const int j   = bid & (q - 1);
      const int i0  = ((bid >> (11 - 2 * s)) << (13 - 2 * s)) + j;
      const float2 w1 = twf(j << (2 * s));
      const float2 w2 = cmulf(w1, w1);
      const float2 w3 = cmulf(w2, w1);
      R4DIT(A) R4DIT(B)
    }
  }
  __syncthreads();
}

// single-buffer variant
static __device__ void conv1(float2* A, const float2* __restrict__ Hf) {
  const int tid = threadIdx.x;
  #pragma unroll
  for (int s = 0; s < 6; ++s) {
    const int q = 2048 >> (2 * s);
    __syncthreads();
    #pragma unroll
    for (int r = 0; r < 2; ++r) {
      const int bid = tid + (r << 10);
      const int j   = bid & (q - 1);
      const int i0  = ((bid >> (11 - 2 * s)) << (13 - 2 * s)) + j;
      const float2 w1 = twf(j << (2 * s));
      const float2 w2 = cmulf(w1, w1);
      const float2 w3 = cmulf(w2, w1);
      R4DIF(A)
    }
  }
  __syncthreads();
  #pragma unroll
  for (int r = 0; r < 4; ++r) {
    const int p = tid + (r << 10);
    const float4 h = reinterpret_cast<const float4*>(Hf)[p];
    reinterpret_cast<float4*>(A)[p] = midpair(reinterpret_cast<float4*>(A)[p], h);
  }
  #pragma unroll
  for (int s = 5; s >= 0; --s) {
    const int q = 2048 >> (2 * s);
    __syncthreads();
    #pragma unroll
    for (int r = 0; r < 2; ++r) {
      const int bid = tid + (r << 10);
      const int j   = bid & (q - 1);
      const int i0  = ((bid >> (11 - 2 * s)) << (13 - 2 * s)) + j;
      const float2 w1 = twf(j << (2 * s));
      const float2 w2 = cmulf(w1, w1);
      const float2 w3 = cmulf(w2, w1);
      R4DIT(A)
    }
  }
  __syncthreads();
}

// ---------------- setup: tables (fp64) + Bluestein filters ----------------
// table-twiddle DIF kept ONLY for setup_filters (must match conv's digit-reversed order)
template <int NT>
static __device__ void fft_dif_tab(float2* buf, const float2* __restrict__ tw) {
  const int tid = threadIdx.x;
  for (int s = 0; s < 6; ++s) {
    const int q = 2048 >> (2 * s);
    __syncthreads();
    for (int r = 0; r < 2048 / NT; ++r) {
      const int bid = tid + r * NT;
      const int j   = bid & (q - 1);
      const int i0  = ((bid >> (11 - 2 * s)) << (13 - 2 * s)) + j;
      const int e   = j << (2 * s);
      const float2 w1 = tw[e], w2 = tw[2 * e], w3 = tw[3 * e];
      R4DIF(buf)
    }
  }
  __syncthreads();
  for (int r = 0; r < 4096 / NT; ++r) {
    const int i0 = (tid + r * NT) << 1;
    const float2 a = buf[i0], b = buf[i0 + 1];
    buf[i0] = cadd(a, b); buf[i0 + 1] = csub(a, b);
  }
  __syncthreads();
}

extern "C" __global__ void setup_tables(float2* ws) {
  const int idx = blockIdx.x * 512 + threadIdx.x;
  if (idx < 4096) {
    const long p = ((long)idx * idx) % 16382;      // j^2 mod 2*8191
    const double th = -M_PI * (double)p / 8191.0;
    double s, c; sincos(th, &s, &c);
    ws[WS_C + idx] = make_float2((float)c, (float)s);
  } else if (idx < 8192) {
    const int j = idx - 4096;
    const long p = ((long)j * j) % 16380;          // j^2 mod 2*8190
    const double th = M_PI * (double)p / 8190.0;
    double s, c; sincos(th, &s, &c);
    ws[WS_D + j] = make_float2((float)c, (float)s);
  } else if (idx < 16384) {
    const int j = idx - 8192;
    const double th = -M_PI * (double)j / 4096.0;  // e^{-2pi i j/8192}
    double s, c; sincos(th, &s, &c);
    ws[WS_TW + j] = make_float2((float)c, (float)s);
  }
}

extern "C" __global__ __launch_bounds__(512, 1) void setup_filters(float2* ws) {
  __shared__ __align__(16) float2 buf[M_];
  const float2* src = ws + (blockIdx.x == 0 ? WS_C : WS_D);
  float2*       dst = ws + (blockIdx.x == 0 ? WS_H1 : WS_H2);
  const float2* tw  = ws + WS_TW;
  for (int i = threadIdx.x; i < M_; i += 512) {
    float2 val = make_float2(0.f, 0.f);
    if (i != 4096) {                       // kernel support |j| <= 4095
      const int jj = (i <= 4095) ? i : (M_ - i);   // chirp is even in j
      const float2 e = src[jj];
      val = make_float2(e.x, -e.y);        // conj(chirp)
    }
    buf[i] = val;
  }
  fft_dif_tab<512>(buf, tw);
  const float sc = 1.0f / 8192.0f;         // fold IFFT scaling into the filter
  for (int i = threadIdx.x; i < M_; i += 512)
    dst[i] = make_float2(buf[i].x * sc, buf[i].y * sc);
}

// ---------------- projection kernel v2: 16-float in-register partials ----------------
// Lane L of a wave covers floats [L*16, L*16+16) of a 1024-float group (= 2 l-rows x 8 h x 64).
// Only a 4-lane (2-stage) shuffle reduce remains: 8x fewer DS ops than the 16-lane version.
extern "C" __global__ __launch_bounds__(256)
void proj_kernel(const float* __restrict__ queries, const float* __restrict__ keys,
                 const float* __restrict__ values,
                 const float* __restrict__ Wq, const float* __restrict__ bq,
                 const float* __restrict__ Wk, const float* __restrict__ bk,
                 const float* __restrict__ Wv, const float* __restrict__ bv,
                 float* __restrict__ q_ws, float* __restrict__ k_ws,
                 float* __restrict__ v_ws)
{
  const int tid  = threadIdx.x;
  const int wave = tid >> 6;           // 0..3
  const int lane = tid & 63;
  const int qt   = lane & 3;           // quarter of a 64-float row
  const int rr   = lane >> 2;          // row-in-group 0..15
  const int hh   = rr & 7;             // head
  const int dl   = rr >> 3;            // l-offset within group (0..1)
  const int blk  = blockIdx.x;         // 2048 blocks
  const int b    = blk >> 6;           // 0..31
  const int lbase = (blk & 63) << 6;   // 0..4032 step 64

  const float* srcs[3] = {queries, keys, values};
  const float* Wsx[3]  = {Wq, Wk, Wv};
  const float* Bsx[3]  = {bq, bk, bv};
  float* dsts[3] = {q_ws, k_ws, v_ws};

  #pragma unroll
  for (int s = 0; s < 3; ++s) {
    const float4* src4 = reinterpret_cast<const float4*>(srcs[s]) + (size_t)b * 524288;
    const float4* W4   = reinterpret_cast<const float4*>(Wsx[s]);
    float4 w[4];
    #pragma unroll
    for (int j = 0; j < 4; ++j) w[j] = W4[qt * 4 + j];
    const float bias = Bsx[s][0];
    float* dst = dsts[s] + ((size_t)(b * 8 + hh) << 12);

    #pragma unroll
    for (int st = 0; st < 4; ++st) {
      const int l0a = lbase + st * 16 + wave * 2;   // group A: rows l0a, l0a+1
      const int l0b = l0a + 8;                      // group B: rows l0b, l0b+1
      const float4* pa = src4 + (size_t)l0a * 128 + lane * 4;
      const float4* pb = src4 + (size_t)l0b * 128 + lane * 4;
      float4 xa[4], xb[4];
      #pragma unroll
      for (int j = 0; j < 4; ++j) xa[j] = pa[j];
      #pragma unroll
      for (int j = 0; j < 4; ++j) xb[j] = pb[j];
      float fa = 0.f, fb = 0.f;
      #pragma unroll
      for (int j = 0; j < 4; ++j) {
        fa += xa[j].x * w[j].x + xa[j].y * w[j].y + xa[j].z * w[j].z + xa[j].w * w[j].w;
        fb += xb[j].x * w[j].x + xb[j].y * w[j].y + xb[j].z * w[j].z + xb[j].w * w[j].w;
      }
      fa += __shfl_xor(fa, 1); fb += __shfl_xor(fb, 1);
      fa += __shfl_xor(fa, 2); fb += __shfl_xor(fb, 2);
      if (qt == 0) {
        dst[l0a + dl] = fa + bias;
        dst[l0b + dl] = fb + bias;
      }
    }
  }
}

// ---------------- main kernel: CZT scores + topk + softmax + gather ----------------
extern "C" __global__ __launch_bounds__(1024, 1)
void autocorr_main(const float2* __restrict__ ws,
                   const float* __restrict__ q_ws, const float* __restrict__ k_ws,
                   const float* __restrict__ v_ws, float* __restrict__ outp)
{
  __shared__ __align__(16) float2 bufA[M_];   // 64 KB (K path, then inverse-CZT)
  __shared__ __align__(16) float2 bufB[M_];   // 64 KB (Q path)
  __shared__ float  v_lds[L_];                // 16 KB
  __shared__ float  cand_v[16 * KK];
  __shared__ int    cand_i[16 * KK];
  __shared__ float  w_sh[KK];
  __shared__ int    i_sh[KK];

  const int tid = threadIdx.x;
  const int bh  = blockIdx.x;

  const float2* c_t = ws + WS_C;
  const float2* d_t = ws + WS_D;
  const float2* H1  = ws + WS_H1;
  const float2* H2  = ws + WS_H2;
  const float* qrow = q_ws + ((size_t)bh << 12);
  const float* krow = k_ws + ((size_t)bh << 12);
  const float* vrow = v_ws + ((size_t)bh << 12);

  // v into LDS; chirp-premultiplied k (bufA) / q (bufB); zero-pad 4096..8191
  {
    const float4 v4 = reinterpret_cast<const float4*>(vrow)[tid];
    reinterpret_cast<float4*>(v_lds)[tid] = v4;
    const float4 k4 = reinterpret_cast<const float4*>(krow)[tid];
    const float4 q4 = reinterpret_cast<const float4*>(qrow)[tid];
    const float4 c01 = reinterpret_cast<const float4*>(c_t)[2 * tid];
    const float4 c23 = reinterpret_cast<const float4*>(c_t)[2 * tid + 1];
    float4* A4 = reinterpret_cast<float4*>(bufA);
    float4* B4 = reinterpret_cast<float4*>(bufB);
    A4[2 * tid]     = make_float4(k4.x * c01.x, k4.x * c01.y, k4.y * c01.z, k4.y * c01.w);
    A4[2 * tid + 1] = make_float4(k4.z * c23.x, k4.z * c23.y, k4.w * c23.z, k4.w * c23.w);
    B4[2 * tid]     = make_float4(q4.x * c01.x, q4.x * c01.y, q4.y * c01.z, q4.y * c01.w);
    B4[2 * tid + 1] = make_float4(q4.z * c23.x, q4.z * c23.y, q4.w * c23.z, q4.w * c23.w);
    const float4 z = make_float4(0.f, 0.f, 0.f, 0.f);
    A4[2048 + tid] = z; A4[3072 + tid] = z;
    B4[2048 + tid] = z; B4[3072 + tid] = z;
  }

  // ------- fused forward CZT for K (A) and Q (B) -------
  conv2(bufA, bufB, H1);

  // ------- F = (c.Q) * conj(c.K); build g.d into bufA (inverse-CZT input) -------
  #pragma unroll
  for (int r = 0; r < 4; ++r) {
    const int m = tid + (r << 10);
    const float2 cc = c_t[m];
    const float2 K = cmulf(cc, bufA[m]);
    const float2 Q = cmulf(cc, bufB[m]);
    const float2 F = cmulcf(Q, K);
    float2 g;
    if (m == 0 || m == 4095) g = make_float2(F.x, 0.f);   // DC/Nyquist: Im dropped
    else                     g = make_float2(2.f * F.x, 2.f * F.y);
    bufA[m] = cmulf(g, d_t[m]);
  }
  #pragma unroll
  for (int r = 4; r < 8; ++r) bufA[tid + (r << 10)] = make_float2(0.f, 0.f);

  // ------- inverse via irfft_8190 semantics: y_t = Re(d_t * IFFT(FFT(g.d) . H2)[t]) -------
  conv1(bufA, H2);

  // ---------------- scores + per-wave top-45 ----------------
  const float SCALE = (float)(1.0 / (8190.0 * 4096.0));   // /8190 (irfft) then /4096 (L)
  float svv[4]; int sii[4];
  #pragma unroll
  for (int r = 0; r < 4; ++r) {
    const int t = tid + (r << 10);
    const float2 Z = cmulf(d_t[t], bufA[t]);
    svv[r] = Z.x * SCALE;
    sii[r] = t;
  }
  const int lane = tid & 63, wv = tid >> 6;   // 16 waves
  for (int it = 0; it < KK; ++it) {
    float bvv = -FLT_MAX; int bii = 0x7fffffff;
    #pragma unroll
    for (int c = 0; c < 4; ++c)
      if (svv[c] > bvv || (svv[c] == bvv && sii[c] < bii)) { bvv = svv[c]; bii = sii[c]; }
    #pragma unroll
    for (int off = 1; off < 64; off <<= 1) {
      const float ov = __shfl_xor(bvv, off);
      const int   oi = __shfl_xor(bii, off);
      if (ov > bvv || (ov == bvv && oi < bii)) { bvv = ov; bii = oi; }
    }
    #pragma unroll
    for (int c = 0; c < 4; ++c) if (sii[c] == bii) svv[c] = -FLT_MAX;
    if (lane == 0) { cand_v[wv * KK + it] = bvv; cand_i[wv * KK + it] = bii; }
  }
  __syncthreads();

  // ---------------- merge 16x45 + softmax (wave 0) ----------------
  if (tid < 64) {
    float mv[12]; int mi[12];
    #pragma unroll
    for (int c = 0; c < 12; ++c) {
      const int id = tid + 64 * c;
      if (id < 16 * KK) { mv[c] = cand_v[id]; mi[c] = cand_i[id]; }
      else              { mv[c] = -FLT_MAX;   mi[c] = 0x7fffffff; }
    }
    float m0 = 0.f, sum = 0.f, myv = -FLT_MAX; int myi = 0;
    for (int it = 0; it < KK; ++it) {
      float bvv = -FLT_MAX; int bii = 0x7fffffff;
      #pragma unroll
      for (int c = 0; c < 12; ++c)
        if (mv[c] > bvv || (mv[c] == bvv && mi[c] < bii)) { bvv = mv[c]; bii = mi[c]; }
      #pragma unroll
      for (int off = 1; off < 64; off <<= 1) {
        const float ov = __shfl_xor(bvv, off);
        const int   oi = __shfl_xor(bii, off);
        if (ov > bvv || (ov == bvv && oi < bii)) { bvv = ov; bii = oi; }
      }
      if (it == 0) m0 = bvv;
      sum += expf(bvv - m0);               // identical on all lanes
      if (tid == it) { myv = bvv; myi = bii; }
      #pragma unroll
      for (int c = 0; c < 12; ++c) if (mi[c] == bii) mv[c] = -FLT_MAX;
    }
    if (tid < KK) { w_sh[tid] = expf(myv - m0) / sum; i_sh[tid] = myi; }
  }
  __syncthreads();

  // ---------------- gather: out[t] = sum_j w_j * v[(idx_j + t) & 4095] ------------
  {
    float acc[4] = {0, 0, 0, 0};
    for (int j = 0; j < KK; ++j) {
      const float wj = w_sh[j];
      const int   bse = i_sh[j] + tid;
      #pragma unroll
      for (int r = 0; r < 4; ++r)
        acc[r] = fmaf(wj, v_lds[(bse + (r << 10)) & (L_ - 1)], acc[r]);
    }
    float* op = outp + ((size_t)bh << 12);
    #pragma unroll
    for (int r = 0; r < 4; ++r) op[tid + (r << 10)] = acc[r];
  }
}

extern "C" void kernel_launch(void* const* d_in, const int* in_sizes, int n_in,
                              void* d_out, int out_size, void* d_ws, size_t ws_size,
                              hipStream_t stream) {
  const float* queries = (const float*)d_in[0];
  const float* keys    = (const float*)d_in[1];
  const float* values  = (const float*)d_in[2];
  const float* Wq = (const float*)d_in[3];
  const float* bq = (const float*)d_in[4];
  const float* Wk = (const float*)d_in[5];
  const float* bk = (const float*)d_in[6];
  const float* Wv = (const float*)d_in[7];
  const float* bv = (const float*)d_in[8];
  float2* ws = (float2*)d_ws;
  float* q_ws = (float*)d_ws + 2 * WS_QKV;
  float* k_ws = q_ws + (1 << 20);
  float* v_ws = k_ws + (1 << 20);
  float* out = (float*)d_out;

  hipLaunchKernelGGL(setup_tables,  dim3(32), dim3(512), 0, stream, ws);
  hipLaunchKernelGGL(setup_filters, dim3(2),  dim3(512), 0, stream, ws);
  hipLaunchKernelGGL(proj_kernel,   dim3(2048), dim3(256), 0, stream,
                     queries, keys, values, Wq, bq, Wk, bk, Wv, bv, q_ws, k_ws, v_ws);
  hipLaunchKernelGGL(autocorr_main, dim3(256), dim3(1024), 0, stream,
                     ws, q_ws, k_ws, v_ws, out);
}